// Round 7
// baseline (684.547 us; speedup 1.0000x reference)
//
#include <hip/hip_runtime.h>
#include <hip/hip_bf16.h>

// Problem constants
#define NB 4
#define NC 256
#define ND 32
#define WH 1024          // W*H
#define DWH 32768        // D*W*H
#define KTOT 1024        // 4 modalities * 256 channels

typedef __attribute__((ext_vector_type(8))) short short8;
typedef __attribute__((ext_vector_type(4))) float f32x4;

static __device__ __forceinline__ unsigned short f32_to_bf16(float f) {
    unsigned u = __builtin_bit_cast(unsigned, f);
    u = u + 0x7fff + ((u >> 16) & 1);   // round-to-nearest-even
    return (unsigned short)(u >> 16);
}

static __device__ __forceinline__ unsigned pack_bf16x2(float lo, float hi) {
    return (unsigned)f32_to_bf16(lo) | ((unsigned)f32_to_bf16(hi) << 16);
}

// ---------------------------------------------------------------------------
// Kernel 1: adaptive_avg_pool3d(x,(D,1,1)) == mean over W,H -> pooled[b][c][m][d]
// ---------------------------------------------------------------------------
__global__ __launch_bounds__(256) void pool_kernel(
    const float* __restrict__ i0, const float* __restrict__ i1,
    const float* __restrict__ i2, const float* __restrict__ i3,
    float* __restrict__ pooled)
{
    int bid = blockIdx.x;            // (b*NC + c)*4 + m
    int m   = bid & 3;
    int bc  = bid >> 2;              // b*NC + c
    const float* src = (m == 0 ? i0 : m == 1 ? i1 : m == 2 ? i2 : i3)
                       + (size_t)bc * DWH;
    int t = threadIdx.x;
    int wave = t >> 6, lane = t & 63;

    for (int d = wave; d < ND; d += 4) {
        const float4* row = (const float4*)(src + (size_t)d * WH);
        float s = 0.f;
        #pragma unroll
        for (int j = 0; j < 4; ++j) {
            float4 v = row[lane + 64 * j];
            s += v.x + v.y + v.z + v.w;
        }
        #pragma unroll
        for (int off = 32; off; off >>= 1) s += __shfl_down(s, off, 64);
        if (lane == 0) pooled[bc * 128 + m * 32 + d] = s * (1.0f / 1024.0f);
    }
}

// ---------------------------------------------------------------------------
// Kernel 2: attention weights + effective GEMM A-matrix + effective bias.
// ---------------------------------------------------------------------------
__global__ __launch_bounds__(64) void attn_kernel(
    const float* __restrict__ pooled,
    const float* __restrict__ Wq, const float* __restrict__ bq,
    const float* __restrict__ Wk, const float* __restrict__ bk,
    const float* __restrict__ Wc, const float* __restrict__ bcv,
    unsigned short* __restrict__ Amat, float* __restrict__ beff)
{
    int bc_idx = blockIdx.x;             // b*NC + c
    int lane = threadIdx.x;
    int e = lane & 31;
    const float* P = pooled + bc_idx * 128;

    float q = 0.f, kv[4] = {0.f, 0.f, 0.f, 0.f};
    for (int d = 0; d < 32; ++d) {
        float pq = P[d];
        float wq = Wq[e * 32 + d], wk = Wk[e * 32 + d];
        q += pq * wq;
        #pragma unroll
        for (int m = 0; m < 4; ++m) kv[m] += P[m * 32 + d] * wk;
    }
    q += bq[e];
    #pragma unroll
    for (int m = 0; m < 4; ++m) kv[m] += bk[e];

    float lg[4];
    #pragma unroll
    for (int m = 0; m < 4; ++m) {
        float p = q * kv[m];
        #pragma unroll
        for (int off = 16; off; off >>= 1) p += __shfl_xor(p, off, 32);
        lg[m] = p * 0.17677669529663687f;    // 1/sqrt(32)
    }
    float mx = fmaxf(fmaxf(lg[0], lg[1]), fmaxf(lg[2], lg[3]));
    float ex[4], s = 0.f;
    #pragma unroll
    for (int m = 0; m < 4; ++m) { ex[m] = __expf(lg[m] - mx); s += ex[m]; }
    float a[4];
    #pragma unroll
    for (int m = 0; m < 4; ++m) a[m] = ex[m] / s;

    int c = bc_idx & 255;
    if (lane == 0) {
        float be = 0.f;
        #pragma unroll
        for (int m = 0; m < 4; ++m) be += a[m] * bcv[m * NC + c];
        beff[bc_idx] = be;
    }
    unsigned short* Arow = Amat + (size_t)bc_idx * KTOT;
    #pragma unroll
    for (int j = 0; j < 16; ++j) {
        int k = j * 64 + lane;
        int m = k >> 8, cin = k & 255;
        float v = a[m] * Wc[(m * NC + c) * NC + cin];
        Arow[k] = f32_to_bf16(v);
    }
}

// ---------------------------------------------------------------------------
// Kernel 3: per-batch GEMM, fully covered pipeline:
//   A: LDS double-buffer staged ONE iter ahead via global_load_lds; the
//      sync2 wait is vmcnt(20) = exactly {B(j+1):8, A(j+1):4, B(j+2):8}
//      newer ops, so A(j) is drained without blocking on fresh vmem.
//   B: register prefetch depth 2 (va/vb, loop unrolled x2 for static
//      indexing) -> converted 2 iterations after issue.
//   Nothing in the steady-state loop waits on recently-issued memory.
// ---------------------------------------------------------------------------
#define BM 128
#define BN 128
#define BK 64

static __device__ __forceinline__ int swz(int row, int chunk) {
    // ushort units: row stride 64 ushorts (=128B), chunk = 8 ushorts (=16B)
    return row * 64 + ((chunk ^ (row & 7)) << 3);
}

#define GEMM_ITER(J, VC, ARD, AWR)                                            \
  {                                                                           \
    __builtin_amdgcn_s_barrier();            /* sync1: prev compute done */   \
    __builtin_amdgcn_sched_barrier(0);                                        \
    int ja_ = ((J) + 1 < 16) ? (J) + 1 : 15;                                  \
    _Pragma("unroll")                                                         \
    for (int p_ = 0; p_ < 4; ++p_)                                            \
      __builtin_amdgcn_global_load_lds(                                       \
          (const __attribute__((address_space(1))) unsigned int*)             \
              (asrc + (size_t)p_ * 8 * KTOT + ja_ * BK),                      \
          (__attribute__((address_space(3))) unsigned int*)                   \
              ((AWR) + (wave * 32 + p_ * 8) * 64),                            \
          16, 0, 0);                                                          \
    __builtin_amdgcn_sched_barrier(0);                                        \
    uint4 pk_[4];                            /* convert B(J), 2 iters old */  \
    _Pragma("unroll")                                                         \
    for (int i_ = 0; i_ < 4; ++i_) {                                          \
      unsigned w0_ = pack_bf16x2(((const float*)&(VC)[0])[i_],                \
                                 ((const float*)&(VC)[1])[i_]);               \
      unsigned w1_ = pack_bf16x2(((const float*)&(VC)[2])[i_],                \
                                 ((const float*)&(VC)[3])[i_]);               \
      unsigned w2_ = pack_bf16x2(((const float*)&(VC)[4])[i_],                \
                                 ((const float*)&(VC)[5])[i_]);               \
      unsigned w3_ = pack_bf16x2(((const float*)&(VC)[6])[i_],                \
                                 ((const float*)&(VC)[7])[i_]);               \
      pk_[i_] = (uint4){w0_, w1_, w2_, w3_};                                  \
    }                                                                         \
    {                                        /* issue B(J+2) -> VC */         \
      int jb_ = ((J) + 2 < 16) ? (J) + 2 : 15;                                \
      int m_ = jb_ >> 2, cb_ = (jb_ & 3) * 64;                                \
      const float* Bb_ = (m_ == 0 ? i0 : m_ == 1 ? i1 : m_ == 2 ? i2 : i3)    \
                         + ((size_t)b * NC + cb_) * DWH + x0;                 \
      _Pragma("unroll")                                                       \
      for (int j_ = 0; j_ < 8; ++j_)                                          \
        (VC)[j_] = *(const float4*)(Bb_ + (size_t)(kb + j_) * DWH + xq * 4);  \
    }                                                                         \
    __builtin_amdgcn_sched_barrier(0);                                        \
    _Pragma("unroll")                                                         \
    for (int i_ = 0; i_ < 4; ++i_)                                            \
      *(uint4*)(&Bs[swz(xq * 4 + i_, t >> 5)]) = pk_[i_];                     \
    asm volatile("s_waitcnt vmcnt(20) lgkmcnt(0)" ::: "memory");              \
    __builtin_amdgcn_s_barrier();            /* sync2: As(J)/Bs(J) ready */   \
    __builtin_amdgcn_sched_barrier(0);                                        \
    _Pragma("unroll")                                                         \
    for (int kk_ = 0; kk_ < 2; ++kk_) {                                       \
      int q_ = kk_ * 4 + lk;                                                  \
      short8 af_[4], bf_[4];                                                  \
      _Pragma("unroll")                                                       \
      for (int mi_ = 0; mi_ < 4; ++mi_)                                       \
        af_[mi_] = *(const short8*)(&(ARD)[swz(wr * 64 + mi_ * 16 + lrow, q_)]); \
      _Pragma("unroll")                                                       \
      for (int ni_ = 0; ni_ < 4; ++ni_)                                       \
        bf_[ni_] = *(const short8*)(&Bs[swz(wc * 64 + ni_ * 16 + lrow, q_)]); \
      __builtin_amdgcn_s_setprio(1);                                          \
      _Pragma("unroll")                                                       \
      for (int mi_ = 0; mi_ < 4; ++mi_)                                       \
        _Pragma("unroll")                                                     \
        for (int ni_ = 0; ni_ < 4; ++ni_)                                     \
          acc[mi_][ni_] = __builtin_amdgcn_mfma_f32_16x16x32_bf16(            \
              af_[mi_], bf_[ni_], acc[mi_][ni_], 0, 0, 0);                    \
      __builtin_amdgcn_s_setprio(0);                                          \
    }                                                                         \
  }

__global__ __launch_bounds__(256, 3) void gemm_kernel(
    const float* __restrict__ i0, const float* __restrict__ i1,
    const float* __restrict__ i2, const float* __restrict__ i3,
    const unsigned short* __restrict__ Amat,
    const float* __restrict__ beff,
    float* __restrict__ out)
{
    __shared__ __align__(16) short As[2 * BM * BK];   // A double-buffer, 32KB
    __shared__ __align__(16) short Bs[BN * BK];       // B single, 16KB

    // XCD-aware bijective swizzle: 2048 blocks, 8 XCDs, 256 per XCD
    int raw = blockIdx.x;
    int sb  = (raw & 7) * 256 + (raw >> 3);
    int ot = sb & 1;                 // o-tile (fastest -> pairs share B panel)
    int xt = (sb >> 1) & 255;        // x-tile
    int b  = sb >> 9;                // batch
    int o0 = ot * BM, x0 = xt * BN;

    const unsigned short* Ab = Amat + ((size_t)b * NC + o0) * KTOT;

    int t = threadIdx.x;
    int wave = t >> 6, lane = t & 63;
    int wr = wave >> 1, wc = wave & 1;
    int lrow = lane & 15, lk = lane >> 4;

    f32x4 acc[4][4];
    #pragma unroll
    for (int mi = 0; mi < 4; ++mi)
        #pragma unroll
        for (int ni = 0; ni < 4; ++ni)
            acc[mi][ni] = (f32x4){0.f, 0.f, 0.f, 0.f};

    // B staging mapping: thread t loads float4 (4 x's) for 8 consecutive k's.
    int xq = t & 31;                 // x-group (4 floats each)
    int kb = (t >> 5) * 8;           // k base (0..56)

    // A direct-to-LDS mapping: per instr p, wave covers rows wave*32+p*8..+7,
    // lane -> row offset lane>>3, slot lane&7; source chunk pre-swizzled:
    // q = (lane&7) ^ (lane>>3)  (row&7 == lane>>3).
    int ar = wave * 32 + (lane >> 3);
    int aq = (lane & 7) ^ (lane >> 3);
    const unsigned short* asrc = Ab + (size_t)ar * KTOT + aq * 8;

    short* As0 = As;
    short* As1 = As + BM * BK;

    float4 va[8], vb[8];

    // ---- prologue: issue B(0)->va, A(0)->As0, B(1)->vb ----
    {
        const float* Bb = i0 + (size_t)b * NC * DWH + x0;   // it=0: m=0,cb=0
        #pragma unroll
        for (int j = 0; j < 8; ++j)
            va[j] = *(const float4*)(Bb + (size_t)(kb + j) * DWH + xq * 4);
        #pragma unroll
        for (int p = 0; p < 4; ++p)
            __builtin_amdgcn_global_load_lds(
                (const __attribute__((address_space(1))) unsigned int*)
                    (asrc + (size_t)p * 8 * KTOT),
                (__attribute__((address_space(3))) unsigned int*)
                    (As0 + (wave * 32 + p * 8) * 64),
                16, 0, 0);
        const float* Bb1 = i0 + ((size_t)b * NC + 64) * DWH + x0;  // it=1
        #pragma unroll
        for (int j = 0; j < 8; ++j)
            vb[j] = *(const float4*)(Bb1 + (size_t)(kb + j) * DWH + xq * 4);
    }

    #pragma unroll 1
    for (int it2 = 0; it2 < 8; ++it2) {
        int it = it2 * 2;
        GEMM_ITER(it,     va, As0, As1);
        GEMM_ITER(it + 1, vb, As1, As0);
    }

    // ---- epilogue: add bias, store fp32 ----
    // C/D layout (16x16x32): col = lane&15, row = (lane>>4)*4 + reg
    const float* beff_b = beff + b * NC + o0;
    float* outb = out + ((size_t)b * NC + o0) * DWH + x0;
    #pragma unroll
    for (int mi = 0; mi < 4; ++mi) {
        #pragma unroll
        for (int r4 = 0; r4 < 4; ++r4) {
            int row = wr * 64 + mi * 16 + lk * 4 + r4;
            float bias = beff_b[row];
            float* orow = outb + (size_t)row * DWH;
            #pragma unroll
            for (int ni = 0; ni < 4; ++ni) {
                int col = wc * 64 + ni * 16 + lrow;
                orow[col] = acc[mi][ni][r4] + bias;
            }
        }
    }
}

// ---------------------------------------------------------------------------
extern "C" void kernel_launch(void* const* d_in, const int* in_sizes, int n_in,
                              void* d_out, int out_size, void* d_ws, size_t ws_size,
                              hipStream_t stream) {
    const float* m1 = (const float*)d_in[0];
    const float* m2 = (const float*)d_in[1];
    const float* m3 = (const float*)d_in[2];
    const float* m4 = (const float*)d_in[3];
    const float* Wq = (const float*)d_in[4];
    const float* bq = (const float*)d_in[5];
    const float* Wk = (const float*)d_in[6];
    const float* bk = (const float*)d_in[7];
    const float* Wc = (const float*)d_in[8];
    const float* bcv = (const float*)d_in[9];
    float* out = (float*)d_out;

    float* pooled        = (float*)d_ws;                                // 512 KB
    unsigned short* Amat = (unsigned short*)((char*)d_ws + 524288);     // 2 MB
    float* beff          = (float*)((char*)d_ws + 524288 + 2097152);    // 4 KB

    pool_kernel<<<NB * NC * 4, 256, 0, stream>>>(m1, m2, m3, m4, pooled);
    attn_kernel<<<NB * NC, 64, 0, stream>>>(pooled, Wq, bq, Wk, bk, Wc, bcv,
                                            Amat, beff);
    gemm_kernel<<<(NB) * (NC / BM) * (DWH / BN), 256, 0, stream>>>(
        m1, m2, m3, m4, Amat, beff, out);
}

// Round 8
// 269.587 us; speedup vs baseline: 2.5392x; 2.5392x over previous
//
#include <hip/hip_runtime.h>
#include <hip/hip_bf16.h>

// Problem constants
#define NB 4
#define NC 256
#define ND 32
#define WH 1024          // W*H
#define DWH 32768        // D*W*H
#define KTOT 1024        // 4 modalities * 256 channels

typedef __attribute__((ext_vector_type(8))) short short8;
typedef __attribute__((ext_vector_type(4))) float f32x4;

static __device__ __forceinline__ unsigned short f32_to_bf16(float f) {
    unsigned u = __builtin_bit_cast(unsigned, f);
    u = u + 0x7fff + ((u >> 16) & 1);   // round-to-nearest-even
    return (unsigned short)(u >> 16);
}

static __device__ __forceinline__ unsigned pack_bf16x2(float lo, float hi) {
    return (unsigned)f32_to_bf16(lo) | ((unsigned)f32_to_bf16(hi) << 16);
}

// ---------------------------------------------------------------------------
// Kernel 1: adaptive_avg_pool3d(x,(D,1,1)) == mean over W,H -> pooled[b][c][m][d]
// ---------------------------------------------------------------------------
__global__ __launch_bounds__(256) void pool_kernel(
    const float* __restrict__ i0, const float* __restrict__ i1,
    const float* __restrict__ i2, const float* __restrict__ i3,
    float* __restrict__ pooled)
{
    int bid = blockIdx.x;            // (b*NC + c)*4 + m
    int m   = bid & 3;
    int bc  = bid >> 2;              // b*NC + c
    const float* src = (m == 0 ? i0 : m == 1 ? i1 : m == 2 ? i2 : i3)
                       + (size_t)bc * DWH;
    int t = threadIdx.x;
    int wave = t >> 6, lane = t & 63;

    for (int d = wave; d < ND; d += 4) {
        const float4* row = (const float4*)(src + (size_t)d * WH);
        float s = 0.f;
        #pragma unroll
        for (int j = 0; j < 4; ++j) {
            float4 v = row[lane + 64 * j];
            s += v.x + v.y + v.z + v.w;
        }
        #pragma unroll
        for (int off = 32; off; off >>= 1) s += __shfl_down(s, off, 64);
        if (lane == 0) pooled[bc * 128 + m * 32 + d] = s * (1.0f / 1024.0f);
    }
}

// ---------------------------------------------------------------------------
// Kernel 2: attention weights + effective GEMM A-matrix + effective bias.
// ---------------------------------------------------------------------------
__global__ __launch_bounds__(64) void attn_kernel(
    const float* __restrict__ pooled,
    const float* __restrict__ Wq, const float* __restrict__ bq,
    const float* __restrict__ Wk, const float* __restrict__ bk,
    const float* __restrict__ Wc, const float* __restrict__ bcv,
    unsigned short* __restrict__ Amat, float* __restrict__ beff)
{
    int bc_idx = blockIdx.x;             // b*NC + c
    int lane = threadIdx.x;
    int e = lane & 31;
    const float* P = pooled + bc_idx * 128;

    float q = 0.f, kv[4] = {0.f, 0.f, 0.f, 0.f};
    for (int d = 0; d < 32; ++d) {
        float pq = P[d];
        float wq = Wq[e * 32 + d], wk = Wk[e * 32 + d];
        q += pq * wq;
        #pragma unroll
        for (int m = 0; m < 4; ++m) kv[m] += P[m * 32 + d] * wk;
    }
    q += bq[e];
    #pragma unroll
    for (int m = 0; m < 4; ++m) kv[m] += bk[e];

    float lg[4];
    #pragma unroll
    for (int m = 0; m < 4; ++m) {
        float p = q * kv[m];
        #pragma unroll
        for (int off = 16; off; off >>= 1) p += __shfl_xor(p, off, 32);
        lg[m] = p * 0.17677669529663687f;    // 1/sqrt(32)
    }
    float mx = fmaxf(fmaxf(lg[0], lg[1]), fmaxf(lg[2], lg[3]));
    float ex[4], s = 0.f;
    #pragma unroll
    for (int m = 0; m < 4; ++m) { ex[m] = __expf(lg[m] - mx); s += ex[m]; }
    float a[4];
    #pragma unroll
    for (int m = 0; m < 4; ++m) a[m] = ex[m] / s;

    int c = bc_idx & 255;
    if (lane == 0) {
        float be = 0.f;
        #pragma unroll
        for (int m = 0; m < 4; ++m) be += a[m] * bcv[m * NC + c];
        beff[bc_idx] = be;
    }
    unsigned short* Arow = Amat + (size_t)bc_idx * KTOT;
    #pragma unroll
    for (int j = 0; j < 16; ++j) {
        int k = j * 64 + lane;
        int m = k >> 8, cin = k & 255;
        float v = a[m] * Wc[(m * NC + c) * NC + cin];
        Arow[k] = f32_to_bf16(v);
    }
}

// ---------------------------------------------------------------------------
// Kernel 3: per-batch GEMM, 256x128 tile, 8 waves (4Mx2N, wave-tile 64x64),
// 2 phases per K-tile of 64. A: LDS dbuf staged 1 tile ahead (gload_lds,
// pre-swizzled source). B: reg-staged (8 x float2), converted to bf16 and
// written to B LDS dbuf; B(t+2) loads stay in flight across the tile
// boundary -> vmcnt(8) only once per K-tile. B read ONCE per byte (BM=256).
// ---------------------------------------------------------------------------
#define BM 256
#define BN 128
#define BK 64

static __device__ __forceinline__ int swz(int row, int chunk) {
    // ushort units: row stride 64 ushorts (=128B), chunk = 8 ushorts (=16B)
    return row * 64 + ((chunk ^ (row & 7)) << 3);
}

// One K-tile (t): phase1 {frag kk=0; issue A(t+1); barrier}  phase2 {frag
// kk=1; convert VC=B(t+1)->Bnext; issue B(t+2)->VN; lgkm0 vmcnt(8) barrier}
#define K_TILE(T, VC, VN)                                                     \
  {                                                                           \
    const short* Acur_ = As + ((T) & 1) * (BM * BK);                          \
    const short* Bcur_ = Bs + ((T) & 1) * (BN * BK);                          \
    short* Anx_ = As + (((T) + 1) & 1) * (BM * BK);                           \
    short* Bnx_ = Bs + (((T) + 1) & 1) * (BN * BK);                           \
    /* ---- phase 1: kk=0 ---- */                                             \
    {                                                                         \
      short8 af_[4], bf_[4];                                                  \
      _Pragma("unroll")                                                       \
      for (int mi_ = 0; mi_ < 4; ++mi_)                                       \
        af_[mi_] = *(const short8*)(&Acur_[swz(wr * 64 + mi_ * 16 + lrow, lk)]); \
      _Pragma("unroll")                                                       \
      for (int ni_ = 0; ni_ < 4; ++ni_)                                       \
        bf_[ni_] = *(const short8*)(&Bcur_[swz(wc * 64 + ni_ * 16 + lrow, lk)]); \
      int ja_ = ((T) + 1 < 16) ? (T) + 1 : 15;                                \
      _Pragma("unroll")                                                       \
      for (int p_ = 0; p_ < 4; ++p_)                                          \
        __builtin_amdgcn_global_load_lds(                                     \
            (const __attribute__((address_space(1))) unsigned int*)           \
                (asrc + (size_t)p_ * 8 * KTOT + ja_ * BK),                    \
            (__attribute__((address_space(3))) unsigned int*)                 \
                (Anx_ + (wave * 32 + p_ * 8) * 64),                           \
            16, 0, 0);                                                        \
      __builtin_amdgcn_sched_barrier(0);                                      \
      __builtin_amdgcn_s_setprio(1);                                          \
      _Pragma("unroll")                                                       \
      for (int mi_ = 0; mi_ < 4; ++mi_)                                       \
        _Pragma("unroll")                                                     \
        for (int ni_ = 0; ni_ < 4; ++ni_)                                     \
          acc[mi_][ni_] = __builtin_amdgcn_mfma_f32_16x16x32_bf16(            \
              af_[mi_], bf_[ni_], acc[mi_][ni_], 0, 0, 0);                    \
      __builtin_amdgcn_s_setprio(0);                                          \
      __builtin_amdgcn_s_barrier();                                           \
      __builtin_amdgcn_sched_barrier(0);                                      \
    }                                                                         \
    /* ---- phase 2: kk=1 ---- */                                             \
    {                                                                         \
      short8 af_[4], bf_[4];                                                  \
      _Pragma("unroll")                                                       \
      for (int mi_ = 0; mi_ < 4; ++mi_)                                       \
        af_[mi_] = *(const short8*)(&Acur_[swz(wr * 64 + mi_ * 16 + lrow, 4 + lk)]); \
      _Pragma("unroll")                                                       \
      for (int ni_ = 0; ni_ < 4; ++ni_)                                       \
        bf_[ni_] = *(const short8*)(&Bcur_[swz(wc * 64 + ni_ * 16 + lrow, 4 + lk)]); \
      {  /* issue B(T+2) -> VN (8 vmem, newest) */                            \
        int jb_ = ((T) + 2 < 16) ? (T) + 2 : 15;                              \
        int m_ = jb_ >> 2, cb_ = (jb_ & 3) * 64;                              \
        const float* Bb_ = (m_ == 0 ? i0 : m_ == 1 ? i1 : m_ == 2 ? i2 : i3)  \
                           + ((size_t)b * NC + cb_) * DWH + x0;               \
        _Pragma("unroll")                                                     \
        for (int j_ = 0; j_ < 8; ++j_)                                        \
          (VN)[j_] = *(const float2*)(Bb_ + (size_t)(kh * 8 + j_) * DWH + xg * 2); \
      }                                                                       \
      /* convert VC = B(T+1) -> Bnext (2 x b128) */                           \
      uint4 p0_ = (uint4){pack_bf16x2((VC)[0].x, (VC)[1].x),                  \
                          pack_bf16x2((VC)[2].x, (VC)[3].x),                  \
                          pack_bf16x2((VC)[4].x, (VC)[5].x),                  \
                          pack_bf16x2((VC)[6].x, (VC)[7].x)};                 \
      uint4 p1_ = (uint4){pack_bf16x2((VC)[0].y, (VC)[1].y),                  \
                          pack_bf16x2((VC)[2].y, (VC)[3].y),                  \
                          pack_bf16x2((VC)[4].y, (VC)[5].y),                  \
                          pack_bf16x2((VC)[6].y, (VC)[7].y)};                 \
      *(uint4*)(&Bnx_[swz(xg * 2 + 0, kh)]) = p0_;                            \
      *(uint4*)(&Bnx_[swz(xg * 2 + 1, kh)]) = p1_;                            \
      __builtin_amdgcn_sched_barrier(0);                                      \
      __builtin_amdgcn_s_setprio(1);                                          \
      _Pragma("unroll")                                                       \
      for (int mi_ = 0; mi_ < 4; ++mi_)                                       \
        _Pragma("unroll")                                                     \
        for (int ni_ = 0; ni_ < 4; ++ni_)                                     \
          acc[mi_][ni_] = __builtin_amdgcn_mfma_f32_16x16x32_bf16(            \
              af_[mi_], bf_[ni_], acc[mi_][ni_], 0, 0, 0);                    \
      __builtin_amdgcn_s_setprio(0);                                          \
      /* tile boundary: drain A(T+1) gload_lds + own ds_writes; keep B(T+2) */ \
      asm volatile("s_waitcnt vmcnt(8) lgkmcnt(0)" ::: "memory");             \
      __builtin_amdgcn_s_barrier();                                           \
      __builtin_amdgcn_sched_barrier(0);                                      \
    }                                                                         \
  }

__global__ __launch_bounds__(512, 2) void gemm_kernel(
    const float* __restrict__ i0, const float* __restrict__ i1,
    const float* __restrict__ i2, const float* __restrict__ i3,
    const unsigned short* __restrict__ Amat,
    const float* __restrict__ beff,
    float* __restrict__ out)
{
    __shared__ __align__(16) short As[2 * BM * BK];   // 64KB A dbuf
    __shared__ __align__(16) short Bs[2 * BN * BK];   // 32KB B dbuf

    // XCD-aware bijective swizzle: 1024 blocks, 8 XCDs, 128 per XCD
    int raw = blockIdx.x;
    int sb  = (raw & 7) * 128 + (raw >> 3);
    int xt = sb & 255;               // x-tile (adjacent tiles share A in L2)
    int b  = sb >> 8;                // batch
    int x0 = xt * BN;

    const unsigned short* Ab = Amat + (size_t)b * NC * KTOT;  // full 256 rows

    int t = threadIdx.x;
    int wave = t >> 6, lane = t & 63;
    int wr = wave >> 1, wc = wave & 1;      // 4M x 2N wave grid
    int lrow = lane & 15, lk = lane >> 4;

    f32x4 acc[4][4];
    #pragma unroll
    for (int mi = 0; mi < 4; ++mi)
        #pragma unroll
        for (int ni = 0; ni < 4; ++ni)
            acc[mi][ni] = (f32x4){0.f, 0.f, 0.f, 0.f};

    // B staging: thread t loads float2 (2 x's) for 8 consecutive k's.
    int xg = t & 63;                 // x-pair index (0..63 -> x = xg*2, +1)
    int kh = t >> 6;                 // k-chunk (0..7 -> k = kh*8 + j)

    // A direct-to-LDS: instr p of wave w covers rows w*32+p*8..+7;
    // lane -> row offset lane>>3, slot lane&7; source chunk pre-swizzled.
    int ar = wave * 32 + (lane >> 3);
    int aq = (lane & 7) ^ (lane >> 3);
    const unsigned short* asrc = Ab + (size_t)ar * KTOT + aq * 8;

    float2 va[8], vb[8];

    // ---- prologue: A(0)->As0; B(0)->va -> convert -> Bs0; issue B(1)->vb --
    {
        #pragma unroll
        for (int p = 0; p < 4; ++p)
            __builtin_amdgcn_global_load_lds(
                (const __attribute__((address_space(1))) unsigned int*)
                    (asrc + (size_t)p * 8 * KTOT),
                (__attribute__((address_space(3))) unsigned int*)
                    (As + (wave * 32 + p * 8) * 64),
                16, 0, 0);
        const float* Bb = i0 + (size_t)b * NC * DWH + x0;   // tile0: m=0,cb=0
        #pragma unroll
        for (int j = 0; j < 8; ++j)
            va[j] = *(const float2*)(Bb + (size_t)(kh * 8 + j) * DWH + xg * 2);
        uint4 p0 = (uint4){pack_bf16x2(va[0].x, va[1].x),
                           pack_bf16x2(va[2].x, va[3].x),
                           pack_bf16x2(va[4].x, va[5].x),
                           pack_bf16x2(va[6].x, va[7].x)};
        uint4 p1 = (uint4){pack_bf16x2(va[0].y, va[1].y),
                           pack_bf16x2(va[2].y, va[3].y),
                           pack_bf16x2(va[4].y, va[5].y),
                           pack_bf16x2(va[6].y, va[7].y)};
        *(uint4*)(&Bs[swz(xg * 2 + 0, kh)]) = p0;
        *(uint4*)(&Bs[swz(xg * 2 + 1, kh)]) = p1;
        const float* Bb1 = i0 + ((size_t)b * NC + 64) * DWH + x0;  // tile1
        #pragma unroll
        for (int j = 0; j < 8; ++j)
            vb[j] = *(const float2*)(Bb1 + (size_t)(kh * 8 + j) * DWH + xg * 2);
        // A(0) drained (implicit wait for B(0) already covered older A ops,
        // but be explicit): 8 newer ops = B(1)
        asm volatile("s_waitcnt vmcnt(8) lgkmcnt(0)" ::: "memory");
        __builtin_amdgcn_s_barrier();
        __builtin_amdgcn_sched_barrier(0);
    }

    #pragma unroll 1
    for (int t2 = 0; t2 < 8; ++t2) {
        K_TILE(2 * t2,     vb, va);   // converts vb = B(2t2+1), loads va = B(2t2+2)
        K_TILE(2 * t2 + 1, va, vb);   // converts va, loads vb
    }

    // ---- epilogue: add bias, store fp32 ----
    // C/D layout (16x16x32): col = lane&15, row = (lane>>4)*4 + reg
    const float* beff_b = beff + b * NC;
    float* outb = out + (size_t)b * NC * DWH + x0;
    #pragma unroll
    for (int mi = 0; mi < 4; ++mi) {
        #pragma unroll
        for (int r4 = 0; r4 < 4; ++r4) {
            int row = wr * 64 + mi * 16 + lk * 4 + r4;
            float bias = beff_b[row];
            float* orow = outb + (size_t)row * DWH;
            #pragma unroll
            for (int ni = 0; ni < 4; ++ni) {
                int col = wc * 64 + ni * 16 + lrow;
                orow[col] = acc[mi][ni][r4] + bias;
            }
        }
    }
}

// ---------------------------------------------------------------------------
extern "C" void kernel_launch(void* const* d_in, const int* in_sizes, int n_in,
                              void* d_out, int out_size, void* d_ws, size_t ws_size,
                              hipStream_t stream) {
    const float* m1 = (const float*)d_in[0];
    const float* m2 = (const float*)d_in[1];
    const float* m3 = (const float*)d_in[2];
    const float* m4 = (const float*)d_in[3];
    const float* Wq = (const float*)d_in[4];
    const float* bq = (const float*)d_in[5];
    const float* Wk = (const float*)d_in[6];
    const float* bk = (const float*)d_in[7];
    const float* Wc = (const float*)d_in[8];
    const float* bcv = (const float*)d_in[9];
    float* out = (float*)d_out;

    float* pooled        = (float*)d_ws;                                // 512 KB
    unsigned short* Amat = (unsigned short*)((char*)d_ws + 524288);     // 2 MB
    float* beff          = (float*)((char*)d_ws + 524288 + 2097152);    // 4 KB

    pool_kernel<<<NB * NC * 4, 256, 0, stream>>>(m1, m2, m3, m4, pooled);
    attn_kernel<<<NB * NC, 64, 0, stream>>>(pooled, Wq, bq, Wk, bk, Wc, bcv,
                                            Amat, beff);
    gemm_kernel<<<NB * (DWH / BN), 512, 0, stream>>>(
        m1, m2, m3, m4, Amat, beff, out);
}